// Round 4
// baseline (34591.064 us; speedup 1.0000x reference)
//
#include <hip/hip_runtime.h>
#include <hip/hip_cooperative_groups.h>
#include <math.h>

namespace cg = cooperative_groups;

#define B    32
#define H    1024
#define EMB  512
#define V    32000
#define SOS  1
#define NBLK 256
#define NTHR 1024

// PROJ tiling
#define PR   128               // rows per tile
#define PKC  32                // k per chunk
#define NVB  (V / PR)          // 250 tiles
#define NCH  (H / PKC)         // 32 chunks

// ws float offsets.  x/h use layout [k>>2][b][k&3] so GRU reads are float4.
#define OFF_XT 0               // EMB*B      = 16384
#define OFF_HA 16384           // H*B        = 32768
#define OFF_HB 49152           // H*B
#define OFF_P  81920           // 32*512*4   = 65536 (float4 partials [b][tile*2+half])
#define OFF_C  147456          // T*B

__global__ __launch_bounds__(NTHR, 4) void k_fused(
    const float* __restrict__ init_hidden,
    const float* __restrict__ emb,
    const float* __restrict__ wih, const float* __restrict__ bih,
    const float* __restrict__ whh, const float* __restrict__ bhh,
    const float* __restrict__ wout, const float* __restrict__ bout,
    float* __restrict__ out, float* __restrict__ ws, int T)
{
    cg::grid_group grid = cg::this_grid();
    const int t   = threadIdx.x;
    const int blk = blockIdx.x;
    const int gid = blk * NTHR + t;

    float* xT = ws + OFF_XT;
    float* hA = ws + OFF_HA;
    float* hB = ws + OFF_HB;

    __shared__ __align__(16) float smem[10240];   // 40 KiB, phase-aliased

    // ---------------- init (layouts: [k>>2][b][k&3])
    for (int i = gid; i < EMB * B; i += NBLK * NTHR) {
        int k = i >> 5, b = i & 31;
        xT[(k >> 2) * 128 + b * 4 + (k & 3)] = tanhf(emb[(size_t)SOS * EMB + k]);
    }
    for (int i = gid; i < H * B; i += NBLK * NTHR) {
        int j = i >> 5, b = i & 31;
        hA[(j >> 2) * 128 + b * 4 + (j & 3)] = init_hidden[(size_t)b * H + j];
    }
    grid.sync();

    for (int st = 0; st < T; ++st) {
        float* hold = (st & 1) ? hB : hA;
        float* hnew = (st & 1) ? hA : hB;
        float* orow = out + (size_t)st * B * V;

        // ================= GRU =================
        {
            const int ks = t >> 7;            // 8 k-slices of 192
            const int pl = t & 127;
            const int p  = blk * 128 + pl;
            const int b  = p & 31;
            const int j  = p >> 5;

            float ar = 0.f, az = 0.f, ain = 0.f, ahn = 0.f;
            const int k0 = ks * 192, k1 = k0 + 192;

            const int xe = (k1 < EMB) ? k1 : EMB;
            for (int k = k0; k < xe; k += 4) {
                const float4 u = *(const float4*)&xT[(k >> 2) * 128 + b * 4];
                const float4 w0 = *(const float4*)&wih[(size_t)(0 * H + j) * EMB + k];
                const float4 w1 = *(const float4*)&wih[(size_t)(1 * H + j) * EMB + k];
                const float4 w2 = *(const float4*)&wih[(size_t)(2 * H + j) * EMB + k];
                ar  = fmaf(w0.x, u.x, fmaf(w0.y, u.y, fmaf(w0.z, u.z, fmaf(w0.w, u.w, ar))));
                az  = fmaf(w1.x, u.x, fmaf(w1.y, u.y, fmaf(w1.z, u.z, fmaf(w1.w, u.w, az))));
                ain = fmaf(w2.x, u.x, fmaf(w2.y, u.y, fmaf(w2.z, u.z, fmaf(w2.w, u.w, ain))));
            }
            const int hs = (k0 > EMB) ? k0 : EMB;
            for (int k = hs; k < k1; k += 4) {
                const int kh = k - EMB;
                const float4 u = *(const float4*)&hold[(kh >> 2) * 128 + b * 4];
                const float4 w0 = *(const float4*)&whh[(size_t)(0 * H + j) * H + kh];
                const float4 w1 = *(const float4*)&whh[(size_t)(1 * H + j) * H + kh];
                const float4 w2 = *(const float4*)&whh[(size_t)(2 * H + j) * H + kh];
                ar  = fmaf(w0.x, u.x, fmaf(w0.y, u.y, fmaf(w0.z, u.z, fmaf(w0.w, u.w, ar))));
                az  = fmaf(w1.x, u.x, fmaf(w1.y, u.y, fmaf(w1.z, u.z, fmaf(w1.w, u.w, az))));
                ahn = fmaf(w2.x, u.x, fmaf(w2.y, u.y, fmaf(w2.z, u.z, fmaf(w2.w, u.w, ahn))));
            }

            float* redg = smem;   // [4][1024]
            redg[0 * 1024 + pl * 8 + ks] = ar;
            redg[1 * 1024 + pl * 8 + ks] = az;
            redg[2 * 1024 + pl * 8 + ks] = ain;
            redg[3 * 1024 + pl * 8 + ks] = ahn;
            __syncthreads();

            if (t < 128) {
                const int pp = blk * 128 + t;
                const int bb = pp & 31, jj = pp >> 5;
                float s0 = 0.f, s1 = 0.f, s2 = 0.f, s3 = 0.f;
#pragma unroll
                for (int q = 0; q < 8; ++q) {
                    s0 += redg[0 * 1024 + t * 8 + q];
                    s1 += redg[1 * 1024 + t * 8 + q];
                    s2 += redg[2 * 1024 + t * 8 + q];
                    s3 += redg[3 * 1024 + t * 8 + q];
                }
                float gr  = s0 + bih[jj]         + bhh[jj];
                float gz  = s1 + bih[H + jj]     + bhh[H + jj];
                float gin = s2 + bih[2 * H + jj];
                float ghn = s3 + bhh[2 * H + jj];
                float r = 1.f / (1.f + expf(-gr));
                float z = 1.f / (1.f + expf(-gz));
                float n = tanhf(gin + r * ghn);
                const int hidx = (jj >> 2) * 128 + bb * 4 + (jj & 3);
                hnew[hidx] = (1.f - z) * n + z * hold[hidx];
            }
        }
        grid.sync();

        // ================= PROJ (+ softmax partials) =================
        if (blk < NVB) {
            const int rs  = t & 127;
            const int bq  = (t >> 7) & 3;    // 8-b group
            const int ks2 = t >> 9;          // k half of chunk
            const int r0  = blk * PR;
            const int rg  = r0 + rs;

            float acc[8];
#pragma unroll
            for (int i = 0; i < 8; ++i) acc[i] = 0.f;

            float* wb0 = smem;          // [2][128*32]
            float* hb0 = smem + 8192;   // [2][32*32]

            const int rowi = t >> 3;    // staging row 0..127
            const int gw   = t & 7;     // staging k-group
            const int wlo  = rowi * 32 + 4 * (gw ^ (rowi & 7));
            const int kgst = t >> 5;    // h-stage k-group (t<256)
            const int bbst = t & 31;

            float4 sW = make_float4(0.f, 0.f, 0.f, 0.f);
            float4 sH = make_float4(0.f, 0.f, 0.f, 0.f);

            // prologue: chunk 0
            sW = *(const float4*)&wout[(size_t)(r0 + rowi) * H + gw * 4];
            if (t < 256) sH = *(const float4*)&hnew[(size_t)(0 + kgst) * 128 + bbst * 4];
            *(float4*)&wb0[wlo] = sW;
            if (t < 256) {
                hb0[(kgst * 4 + 0) * 32 + bbst] = sH.x;
                hb0[(kgst * 4 + 1) * 32 + bbst] = sH.y;
                hb0[(kgst * 4 + 2) * 32 + bbst] = sH.z;
                hb0[(kgst * 4 + 3) * 32 + bbst] = sH.w;
            }
            __syncthreads();

            for (int c = 0; c < NCH; ++c) {
                const int cur = c & 1;
                if (c + 1 < NCH) {
                    sW = *(const float4*)&wout[(size_t)(r0 + rowi) * H + (c + 1) * PKC + gw * 4];
                    if (t < 256)
                        sH = *(const float4*)&hnew[(size_t)((c + 1) * 8 + kgst) * 128 + bbst * 4];
                }
                const float* wbuf = wb0 + cur * 4096 + rs * 32;
                const float* hbuf = hb0 + cur * 1024;
#pragma unroll
                for (int q = 0; q < 4; ++q) {
                    const int glin = ks2 * 4 + q;
                    const float4 w = *(const float4*)&wbuf[4 * (glin ^ (rs & 7))];
#pragma unroll
                    for (int jj = 0; jj < 4; ++jj) {
                        const float wv = (jj == 0) ? w.x : (jj == 1) ? w.y : (jj == 2) ? w.z : w.w;
                        const float* hp = hbuf + (glin * 4 + jj) * 32 + bq * 8;
                        const float4 ua = *(const float4*)hp;
                        const float4 ub = *(const float4*)(hp + 4);
                        acc[0] = fmaf(wv, ua.x, acc[0]);
                        acc[1] = fmaf(wv, ua.y, acc[1]);
                        acc[2] = fmaf(wv, ua.z, acc[2]);
                        acc[3] = fmaf(wv, ua.w, acc[3]);
                        acc[4] = fmaf(wv, ub.x, acc[4]);
                        acc[5] = fmaf(wv, ub.y, acc[5]);
                        acc[6] = fmaf(wv, ub.z, acc[6]);
                        acc[7] = fmaf(wv, ub.w, acc[7]);
                    }
                }
                if (c + 1 < NCH) {
                    float* wbn = wb0 + (cur ^ 1) * 4096;
                    float* hbn = hb0 + (cur ^ 1) * 1024;
                    *(float4*)&wbn[wlo] = sW;
                    if (t < 256) {
                        hbn[(kgst * 4 + 0) * 32 + bbst] = sH.x;
                        hbn[(kgst * 4 + 1) * 32 + bbst] = sH.y;
                        hbn[(kgst * 4 + 2) * 32 + bbst] = sH.z;
                        hbn[(kgst * 4 + 3) * 32 + bbst] = sH.w;
                    }
                }
                __syncthreads();
            }

            // combine k-halves (redp aliases smem; last loop barrier protects)
            float* redp = smem;
            if (ks2 == 1) {
                *(float4*)&redp[(bq * 128 + rs) * 8 + 0] = make_float4(acc[0], acc[1], acc[2], acc[3]);
                *(float4*)&redp[(bq * 128 + rs) * 8 + 4] = make_float4(acc[4], acc[5], acc[6], acc[7]);
            }
            __syncthreads();
            if (ks2 == 0) {
                const float bo = bout[rg];
#pragma unroll
                for (int i = 0; i < 8; ++i) {
                    acc[i] += redp[(bq * 128 + rs) * 8 + i] + bo;
                    orow[(size_t)(bq * 8 + i) * V + rg] = acc[i];   // raw logits
                }
                // FIN1: per-wave (64 rows) partials for 8 b's
                float m[8]; int am[8]; float l[8];
#pragma unroll
                for (int i = 0; i < 8; ++i) { m[i] = acc[i]; am[i] = rg; }
                for (int off = 32; off > 0; off >>= 1) {
#pragma unroll
                    for (int i = 0; i < 8; ++i) {
                        float om = __shfl_xor(m[i], off);
                        int   oa = __shfl_xor(am[i], off);
                        if (om > m[i] || (om == m[i] && oa < am[i])) { m[i] = om; am[i] = oa; }
                    }
                }
#pragma unroll
                for (int i = 0; i < 8; ++i) l[i] = expf(acc[i] - m[i]);
                for (int off = 32; off > 0; off >>= 1) {
#pragma unroll
                    for (int i = 0; i < 8; ++i) l[i] += __shfl_xor(l[i], off);
                }
                if ((rs & 63) == 0) {
                    const int half = rs >> 6;
                    float4* wsp4 = (float4*)(ws + OFF_P);
#pragma unroll
                    for (int i = 0; i < 8; ++i)
                        wsp4[(bq * 8 + i) * 512 + blk * 2 + half] =
                            make_float4(m[i], l[i], (float)am[i], 0.f);
                }
            }
        }
        grid.sync();

        // ================= FIN2: combine 500 partials per b (32 blocks) =================
        if (blk < B) {
            const int b = blk;
            float* sm_ = smem;             // original m
            float* sv  = smem + 1024;      // tree m
            int*   si  = (int*)(smem + 2048);
            float* sl  = smem + 3072;
            const float4* wsp4 = (const float4*)(ws + OFF_P);

            float m_ = -3.0e38f, l_ = 0.f; int a_ = 0;
            if (t < 2 * NVB) {
                float4 p = wsp4[b * 512 + t];
                m_ = p.x; l_ = p.y; a_ = (int)p.z;
            }
            sm_[t] = m_; sv[t] = m_; si[t] = a_; sl[t] = l_;
            __syncthreads();
            for (int s = 512; s > 0; s >>= 1) {
                if (t < s) {
                    float ov = sv[t + s]; int oi = si[t + s];
                    if (ov > sv[t] || (ov == sv[t] && oi < si[t])) { sv[t] = ov; si[t] = oi; }
                }
                __syncthreads();
            }
            const float M = sv[0];
            const int TOK = si[0];

            float wsc = sl[t] * expf(sm_[t] - M);
            __syncthreads();
            sl[t] = wsc;
            __syncthreads();
            for (int s = 512; s > 0; s >>= 1) {
                if (t < s) sl[t] += sl[t + s];
                __syncthreads();
            }
            if (t == 0) ws[OFF_C + st * 32 + b] = M + logf(sl[0]);

            if (t < EMB)
                xT[(t >> 2) * 128 + b * 4 + (t & 3)] = tanhf(emb[(size_t)TOK * EMB + t]);
        }
        grid.sync();
    }

    // ================= deferred log-softmax subtract =================
    for (int r = blk; r < T * B; r += NBLK) {
        const float Cc = ws[OFF_C + r];
        float4* row = (float4*)(out + (size_t)r * V);
        for (int v4 = t; v4 < V / 4; v4 += NTHR) {
            float4 x = row[v4];
            x.x -= Cc; x.y -= Cc; x.z -= Cc; x.w -= Cc;
            row[v4] = x;
        }
    }
}

extern "C" void kernel_launch(void* const* d_in, const int* in_sizes, int n_in,
                              void* d_out, int out_size, void* d_ws, size_t ws_size,
                              hipStream_t stream)
{
    const float* p_ih   = (const float*)d_in[0];
    // d_in[1] encoder_outputs unused; d_in[2] tgt_len recovered from out_size
    const float* p_emb  = (const float*)d_in[3];
    const float* p_wih  = (const float*)d_in[4];
    const float* p_bih  = (const float*)d_in[5];
    const float* p_whh  = (const float*)d_in[6];
    const float* p_bhh  = (const float*)d_in[7];
    const float* p_wout = (const float*)d_in[8];
    const float* p_bout = (const float*)d_in[9];
    float* p_out = (float*)d_out;
    float* p_ws  = (float*)d_ws;
    int T = out_size / (B * V);

    void* args[] = { &p_ih, &p_emb, &p_wih, &p_bih, &p_whh, &p_bhh,
                     &p_wout, &p_bout, &p_out, &p_ws, &T };
    hipLaunchCooperativeKernel((void*)k_fused, dim3(NBLK), dim3(NTHR), args, 0, stream);
}

// Round 5
// 10662.025 us; speedup vs baseline: 3.2443x; 3.2443x over previous
//
#include <hip/hip_runtime.h>
#include <hip/hip_cooperative_groups.h>
#include <math.h>

namespace cg = cooperative_groups;

#define B    32
#define H    1024
#define EMB  512
#define V    32000
#define SOS  1
#define NBLK 256
#define NTHR 1024

// PROJ tiling: 250 tiles x 128 rows; K-chunk 32, W single-buffered in LDS,
// full h[1024][32] resident in LDS per block per step.
#define PR   128
#define PKC  32
#define NVB  (V / PR)          // 250
#define NCH  (H / PKC)         // 32

// ws float offsets. x/h layouts: [k>>2][b][k&3] (float4 per (k-quad,b)).
#define OFF_XT 0               // EMB*B = 16384
#define OFF_HA 16384           // H*B
#define OFF_HB 49152           // H*B
#define OFF_P  81920           // float4[32][512] partials (m, l, argmax, 0)
#define OFF_C  147456          // T*B log-softmax constants

#define DSM_BYTES (H * B * 4 + PR * PKC * 4)   // 131072 + 16384 = 147456

typedef float f4v __attribute__((ext_vector_type(4)));

__global__ __launch_bounds__(NTHR, 4) void k_fused(
    const float* __restrict__ init_hidden,
    const float* __restrict__ emb,
    const float* __restrict__ wih, const float* __restrict__ bih,
    const float* __restrict__ whh, const float* __restrict__ bhh,
    const float* __restrict__ wout, const float* __restrict__ bout,
    float* __restrict__ out, float* __restrict__ ws, int T)
{
    cg::grid_group grid = cg::this_grid();
    extern __shared__ __align__(16) float dsm[];   // 144 KiB, phase-aliased

    const int t   = threadIdx.x;
    const int blk = blockIdx.x;
    const int gid = blk * NTHR + t;

    float* xT = ws + OFF_XT;
    float* hA = ws + OFF_HA;
    float* hB = ws + OFF_HB;

    // ---------------- init
    for (int i = gid; i < EMB * B; i += NBLK * NTHR) {
        int k = i >> 5, b = i & 31;
        xT[(k >> 2) * 128 + b * 4 + (k & 3)] = tanhf(emb[(size_t)SOS * EMB + k]);
    }
    for (int i = gid; i < H * B; i += NBLK * NTHR) {
        int j = i >> 5, b = i & 31;
        hA[(j >> 2) * 128 + b * 4 + (j & 3)] = init_hidden[(size_t)b * H + j];
    }
    grid.sync();

    for (int st = 0; st < T; ++st) {
        float* hold = (st & 1) ? hB : hA;
        float* hnew = (st & 1) ? hA : hB;
        float* orow = out + (size_t)st * B * V;

        // ================= GRU =================
        {
            const int ks = t >> 7;            // 8 k-slices of 192
            const int pl = t & 127;
            const int p  = blk * 128 + pl;
            const int b  = p & 31;
            const int j  = p >> 5;

            float ar = 0.f, az = 0.f, ain = 0.f, ahn = 0.f;
            const int k0 = ks * 192, k1 = k0 + 192;

            const int xe = (k1 < EMB) ? k1 : EMB;
            for (int k = k0; k < xe; k += 4) {
                const float4 u = *(const float4*)&xT[(k >> 2) * 128 + b * 4];
                const float4 w0 = *(const float4*)&wih[(size_t)(0 * H + j) * EMB + k];
                const float4 w1 = *(const float4*)&wih[(size_t)(1 * H + j) * EMB + k];
                const float4 w2 = *(const float4*)&wih[(size_t)(2 * H + j) * EMB + k];
                ar  = fmaf(w0.x, u.x, fmaf(w0.y, u.y, fmaf(w0.z, u.z, fmaf(w0.w, u.w, ar))));
                az  = fmaf(w1.x, u.x, fmaf(w1.y, u.y, fmaf(w1.z, u.z, fmaf(w1.w, u.w, az))));
                ain = fmaf(w2.x, u.x, fmaf(w2.y, u.y, fmaf(w2.z, u.z, fmaf(w2.w, u.w, ain))));
            }
            const int hs = (k0 > EMB) ? k0 : EMB;
            for (int k = hs; k < k1; k += 4) {
                const int kh = k - EMB;
                const float4 u = *(const float4*)&hold[(kh >> 2) * 128 + b * 4];
                const float4 w0 = *(const float4*)&whh[(size_t)(0 * H + j) * H + kh];
                const float4 w1 = *(const float4*)&whh[(size_t)(1 * H + j) * H + kh];
                const float4 w2 = *(const float4*)&whh[(size_t)(2 * H + j) * H + kh];
                ar  = fmaf(w0.x, u.x, fmaf(w0.y, u.y, fmaf(w0.z, u.z, fmaf(w0.w, u.w, ar))));
                az  = fmaf(w1.x, u.x, fmaf(w1.y, u.y, fmaf(w1.z, u.z, fmaf(w1.w, u.w, az))));
                ahn = fmaf(w2.x, u.x, fmaf(w2.y, u.y, fmaf(w2.z, u.z, fmaf(w2.w, u.w, ahn))));
            }

            // reduce over ks: padded stride 9 (9 coprime 32 -> conflict-free)
            float* redg = dsm;   // [4][128*9]
            redg[0 * 1152 + pl * 9 + ks] = ar;
            redg[1 * 1152 + pl * 9 + ks] = az;
            redg[2 * 1152 + pl * 9 + ks] = ain;
            redg[3 * 1152 + pl * 9 + ks] = ahn;
            __syncthreads();

            if (t < 128) {
                const int pp = blk * 128 + t;
                const int bb = pp & 31, jj = pp >> 5;
                float s0 = 0.f, s1 = 0.f, s2 = 0.f, s3 = 0.f;
#pragma unroll
                for (int q = 0; q < 8; ++q) {
                    s0 += redg[0 * 1152 + t * 9 + q];
                    s1 += redg[1 * 1152 + t * 9 + q];
                    s2 += redg[2 * 1152 + t * 9 + q];
                    s3 += redg[3 * 1152 + t * 9 + q];
                }
                float gr  = s0 + bih[jj]         + bhh[jj];
                float gz  = s1 + bih[H + jj]     + bhh[H + jj];
                float gin = s2 + bih[2 * H + jj];
                float ghn = s3 + bhh[2 * H + jj];
                float r = 1.f / (1.f + expf(-gr));
                float z = 1.f / (1.f + expf(-gz));
                float n = tanhf(gin + r * ghn);   // r multiplies hh-part only
                const int hidx = (jj >> 2) * 128 + bb * 4 + (jj & 3);
                hnew[hidx] = (1.f - z) * n + z * hold[hidx];
            }
        }
        grid.sync();

        // ================= PROJ (+ FIN1 softmax partials) =================
        if (blk < NVB) {
            const int rs = t & 127;
            const int bq = t >> 7;                 // 0..7, wave-uniform (4 b's each)
            const int r0 = blk * PR;
            const int rg = r0 + rs;

            float* hl = dsm;                       // [1024][32]
            float* wl = dsm + H * B;               // [128*32], XOR-swizzled

            // stage full h into LDS (once per step)
            {
                const int bb = t & 31, kk0 = t >> 5;
#pragma unroll
                for (int it = 0; it < 8; ++it) {
                    const int kk = kk0 + it * 32;
                    const float4 u = *(const float4*)&hnew[kk * 128 + bb * 4];
                    hl[(4 * kk + 0) * 32 + bb] = u.x;
                    hl[(4 * kk + 1) * 32 + bb] = u.y;
                    hl[(4 * kk + 2) * 32 + bb] = u.z;
                    hl[(4 * kk + 3) * 32 + bb] = u.w;
                }
            }
            // stage W chunk 0 (coalesced: 8 rows x 128 B per wave)
            const int rowi = t >> 3, col4 = t & 7;
            const int wlo  = rowi * 32 + 4 * (col4 ^ (rowi & 7));
            float4 pf = *(const float4*)&wout[(size_t)(r0 + rowi) * H + col4 * 4];
            *(float4*)&wl[wlo] = pf;
            __syncthreads();

            float acc[4] = {0.f, 0.f, 0.f, 0.f};

            for (int c = 0; c < NCH; ++c) {
                if (c + 1 < NCH)
                    pf = *(const float4*)&wout[(size_t)(r0 + rowi) * H + (c + 1) * PKC + col4 * 4];
                const float* wb = wl + rs * 32;
                const float* hb = hl + (c * PKC) * 32 + bq * 4;
#pragma unroll
                for (int kq = 0; kq < 8; ++kq) {
                    const float4 w = *(const float4*)&wb[4 * (kq ^ (rs & 7))];
#pragma unroll
                    for (int j = 0; j < 4; ++j) {
                        const float wv = (j == 0) ? w.x : (j == 1) ? w.y : (j == 2) ? w.z : w.w;
                        const float4 hv = *(const float4*)&hb[(kq * 4 + j) * 32];
                        acc[0] = fmaf(wv, hv.x, acc[0]);
                        acc[1] = fmaf(wv, hv.y, acc[1]);
                        acc[2] = fmaf(wv, hv.z, acc[2]);
                        acc[3] = fmaf(wv, hv.w, acc[3]);
                    }
                }
                __syncthreads();            // everyone done reading wl
                if (c + 1 < NCH) *(float4*)&wl[wlo] = pf;
                __syncthreads();            // wl refilled
            }

            // epilogue: bias, nt-store raw logits, FIN1 wave partials
            const float bo = bout[rg];
            float m[4]; int am[4]; float l[4];
#pragma unroll
            for (int i = 0; i < 4; ++i) {
                acc[i] += bo;
                __builtin_nontemporal_store(acc[i], &orow[(size_t)(bq * 4 + i) * V + rg]);
                m[i] = acc[i]; am[i] = rg;
            }
            for (int off = 32; off > 0; off >>= 1) {
#pragma unroll
                for (int i = 0; i < 4; ++i) {
                    float om = __shfl_xor(m[i], off);
                    int   oa = __shfl_xor(am[i], off);
                    if (om > m[i] || (om == m[i] && oa < am[i])) { m[i] = om; am[i] = oa; }
                }
            }
#pragma unroll
            for (int i = 0; i < 4; ++i) l[i] = expf(acc[i] - m[i]);
            for (int off = 32; off > 0; off >>= 1) {
#pragma unroll
                for (int i = 0; i < 4; ++i) l[i] += __shfl_xor(l[i], off);
            }
            if ((t & 63) == 0) {
                const int half = rs >> 6;   // wave covers rows [half*64, +64)
                float4* wsp4 = (float4*)(ws + OFF_P);
#pragma unroll
                for (int i = 0; i < 4; ++i)
                    wsp4[(bq * 4 + i) * 512 + blk * 2 + half] =
                        make_float4(m[i], l[i], (float)am[i], 0.f);
            }
        }
        grid.sync();

        // ================= FIN2: combine 500 partials per b =================
        if (blk < B) {
            const int b = blk;
            float* sm_ = dsm;              // original m
            float* sv  = dsm + 1024;       // tree m
            int*   si  = (int*)(dsm + 2048);
            float* sl  = dsm + 3072;
            const float4* wsp4 = (const float4*)(ws + OFF_P);

            float m_ = -3.0e38f, l_ = 0.f; int a_ = 0;
            if (t < 2 * NVB) {
                float4 p = wsp4[b * 512 + t];
                m_ = p.x; l_ = p.y; a_ = (int)p.z;
            }
            sm_[t] = m_; sv[t] = m_; si[t] = a_; sl[t] = l_;
            __syncthreads();
            for (int s = 512; s > 0; s >>= 1) {
                if (t < s) {
                    float ov = sv[t + s]; int oi = si[t + s];
                    if (ov > sv[t] || (ov == sv[t] && oi < si[t])) { sv[t] = ov; si[t] = oi; }
                }
                __syncthreads();
            }
            const float M = sv[0];
            const int TOK = si[0];

            float wsc = sl[t] * expf(sm_[t] - M);
            __syncthreads();
            sl[t] = wsc;
            __syncthreads();
            for (int s = 512; s > 0; s >>= 1) {
                if (t < s) sl[t] += sl[t + s];
                __syncthreads();
            }
            if (t == 0) ws[OFF_C + st * 32 + b] = M + logf(sl[0]);

            if (t < EMB)
                xT[(t >> 2) * 128 + b * 4 + (t & 3)] = tanhf(emb[(size_t)TOK * EMB + t]);
        }
        grid.sync();
    }

    // ================= deferred log-softmax subtract (nt streams) =================
    for (int r = blk; r < T * B; r += NBLK) {
        const float Cc = ws[OFF_C + r];
        f4v* row = (f4v*)(out + (size_t)r * V);
        for (int v4 = t; v4 < V / 4; v4 += NTHR) {
            f4v x = __builtin_nontemporal_load(&row[v4]);
            x -= Cc;
            __builtin_nontemporal_store(x, &row[v4]);
        }
    }
}

extern "C" void kernel_launch(void* const* d_in, const int* in_sizes, int n_in,
                              void* d_out, int out_size, void* d_ws, size_t ws_size,
                              hipStream_t stream)
{
    const float* p_ih   = (const float*)d_in[0];
    // d_in[1] encoder_outputs unused; d_in[2] tgt_len recovered from out_size
    const float* p_emb  = (const float*)d_in[3];
    const float* p_wih  = (const float*)d_in[4];
    const float* p_bih  = (const float*)d_in[5];
    const float* p_whh  = (const float*)d_in[6];
    const float* p_bhh  = (const float*)d_in[7];
    const float* p_wout = (const float*)d_in[8];
    const float* p_bout = (const float*)d_in[9];
    float* p_out = (float*)d_out;
    float* p_ws  = (float*)d_ws;
    int T = out_size / (B * V);

    // attribute set (idempotent, not a stream op -> graph-capture safe)
    hipFuncSetAttribute((const void*)k_fused,
                        hipFuncAttributeMaxDynamicSharedMemorySize, DSM_BYTES);

    void* args[] = { &p_ih, &p_emb, &p_wih, &p_bih, &p_whh, &p_bhh,
                     &p_wout, &p_bout, &p_out, &p_ws, &T };
    hipLaunchCooperativeKernel((void*)k_fused, dim3(NBLK), dim3(NTHR), args,
                               DSM_BYTES, stream);
}